// Round 1
// baseline (532.088 us; speedup 1.0000x reference)
//
#include <hip/hip_runtime.h>
#include <hip/hip_bf16.h>
#include <type_traits>

typedef __bf16 bf16x8 __attribute__((ext_vector_type(8)));
typedef float floatx4 __attribute__((ext_vector_type(4)));

#define S_LEN 2048
#define D_DIM 128
#define NTOK (2 * 16 * 2048)  // B*H*S = 65536 rows

// ---------------------------------------------------------------------------
// proj_kernel: y[r,e] = (sum_d x[r,d] * W[e,d] + b[e]) * out_scale
// MFMA 16x16x32 bf16, W staged in LDS as bf16. 256 thr = 4 waves, 64 rows/blk.
// ---------------------------------------------------------------------------
template <typename TIN, typename TOUT>
__global__ __launch_bounds__(256) void proj_kernel(
    const TIN* __restrict__ x, const float* __restrict__ W,
    const float* __restrict__ b, TOUT* __restrict__ y, float out_scale) {
  __shared__ alignas(16) __bf16 Wl[128][128];  // 32 KB

  const int tid = threadIdx.x;
  const int wave = tid >> 6, lane = tid & 63;
  const int g = lane >> 4, lr = lane & 15;

  // stage W fp32 -> bf16 (16384 elems; 256 thr x 4 x 16 iters, coalesced)
  for (int it = 0; it < 16; ++it) {
    int lin = it * 1024 + tid * 4;
    float4 w4 = *reinterpret_cast<const float4*>(W + lin);
    int r = lin >> 7, c = lin & 127;
    Wl[r][c]     = (__bf16)w4.x;
    Wl[r][c + 1] = (__bf16)w4.y;
    Wl[r][c + 2] = (__bf16)w4.z;
    Wl[r][c + 3] = (__bf16)w4.w;
  }
  __syncthreads();

  const int rbase = blockIdx.x * 64;
  const int arow = rbase + wave * 16 + lr;  // A-fragment row (lane&15 = M row)

  floatx4 acc[8];
  for (int i = 0; i < 8; ++i) acc[i] = floatx4{0.f, 0.f, 0.f, 0.f};

  for (int kc = 0; kc < 4; ++kc) {  // K = 128 in 4 chunks of 32
    bf16x8 af;
    const TIN* xp = x + (size_t)arow * D_DIM + kc * 32 + g * 8;
    if constexpr (std::is_same<TIN, float>::value) {
      float4 f0 = *reinterpret_cast<const float4*>(xp);
      float4 f1 = *reinterpret_cast<const float4*>(xp + 4);
      af[0] = (__bf16)f0.x; af[1] = (__bf16)f0.y;
      af[2] = (__bf16)f0.z; af[3] = (__bf16)f0.w;
      af[4] = (__bf16)f1.x; af[5] = (__bf16)f1.y;
      af[6] = (__bf16)f1.z; af[7] = (__bf16)f1.w;
    } else {
      af = *reinterpret_cast<const bf16x8*>(xp);
    }
    for (int nt = 0; nt < 8; ++nt) {  // 8 N-tiles of 16 cols
      // B[k=d][n=e] = W[e][d]: lane reads W row e = nt*16+lr, cols kc*32+g*8..+7
      bf16x8 wf = *reinterpret_cast<const bf16x8*>(&Wl[nt * 16 + lr][kc * 32 + g * 8]);
      acc[nt] = __builtin_amdgcn_mfma_f32_16x16x32_bf16(af, wf, acc[nt], 0, 0, 0);
    }
  }

  // C/D layout: col = lane&15, row = (lane>>4)*4 + j   [m89-verified]
  for (int nt = 0; nt < 8; ++nt) {
    int e = nt * 16 + lr;
    float be = b[e];
    for (int j = 0; j < 4; ++j) {
      int row = rbase + wave * 16 + g * 4 + j;
      float val = (acc[nt][j] + be) * out_scale;
      y[(size_t)row * D_DIM + e] = (TOUT)val;
    }
  }
}

// ---------------------------------------------------------------------------
// attn_kernel: flash attention, online softmax. Grid (S/64, B*H), 256 thr.
// Each wave owns 16 Q-rows; block owns 64 Q-rows of one (b,h). KVBLK = 64.
// q is pre-scaled by 1/sqrt(D).
// ---------------------------------------------------------------------------
__global__ __launch_bounds__(256) void attn_kernel(
    const __bf16* __restrict__ q, const __bf16* __restrict__ k,
    const __bf16* __restrict__ v, __bf16* __restrict__ o) {
  __shared__ alignas(16) __bf16 Kl[64][128];       // 16 KB, row-major
  __shared__ alignas(16) __bf16 Vt[128][72];       // 18 KB, V transposed (+pad)
  __shared__ alignas(16) __bf16 Pl[4][16][64];     // 8 KB, per-wave P buffer

  const int tid = threadIdx.x;
  const int wave = tid >> 6, lane = tid & 63;
  const int g = lane >> 4, lr = lane & 15;

  const int bh = blockIdx.y;
  const int qbase = blockIdx.x * 64;
  const __bf16* qp = q + (size_t)bh * S_LEN * D_DIM;
  const __bf16* kp = k + (size_t)bh * S_LEN * D_DIM;
  const __bf16* vp = v + (size_t)bh * S_LEN * D_DIM;

  // Q fragments for this wave's 16 rows (A layout: row=lane&15, k=(lane>>4)*8+i)
  const int qrow = qbase + wave * 16 + lr;
  bf16x8 qf[4];
  for (int kc = 0; kc < 4; ++kc)
    qf[kc] = *reinterpret_cast<const bf16x8*>(qp + (size_t)qrow * D_DIM + kc * 32 + g * 8);

  floatx4 acc[8];  // O accumulator: 8 d-tiles x (4 rows/lane)
  for (int i = 0; i < 8; ++i) acc[i] = floatx4{0.f, 0.f, 0.f, 0.f};
  float m_r[4], l_r[4];
  for (int j = 0; j < 4; ++j) { m_r[j] = -1e30f; l_r[j] = 0.f; }

  for (int kv0 = 0; kv0 < S_LEN; kv0 += 64) {
    __syncthreads();  // previous iteration done reading Kl/Vt
    // cooperative load: K row-major, V transposed. 64x128 each, 8 bf16/thr/iter
    for (int it = 0; it < 4; ++it) {
      int idx = it * 256 + tid;         // 0..1023
      int r = idx >> 4;                 // kv row 0..63
      int c = (idx & 15) * 8;           // col 0..120
      *reinterpret_cast<bf16x8*>(&Kl[r][c]) =
          *reinterpret_cast<const bf16x8*>(kp + (size_t)(kv0 + r) * D_DIM + c);
      bf16x8 vv = *reinterpret_cast<const bf16x8*>(vp + (size_t)(kv0 + r) * D_DIM + c);
      for (int e = 0; e < 8; ++e) Vt[c + e][r] = vv[e];
    }
    __syncthreads();

    // QK^T: S-tile 16 rows x 64 cols -> 4 n-tiles, K-dim 128 -> 4 chunks
    floatx4 s[4];
    for (int nt = 0; nt < 4; ++nt) {
      floatx4 sa = floatx4{0.f, 0.f, 0.f, 0.f};
      for (int kc = 0; kc < 4; ++kc) {
        bf16x8 kf = *reinterpret_cast<const bf16x8*>(&Kl[nt * 16 + lr][kc * 32 + g * 8]);
        sa = __builtin_amdgcn_mfma_f32_16x16x32_bf16(qf[kc], kf, sa, 0, 0, 0);
      }
      s[nt] = sa;
    }

    // online softmax: row (q-local) = g*4 + j, cols = nt*16 + lr
    float scale[4];
    for (int j = 0; j < 4; ++j) {
      float mx = fmaxf(fmaxf(s[0][j], s[1][j]), fmaxf(s[2][j], s[3][j]));
      mx = fmaxf(mx, __shfl_xor(mx, 1));
      mx = fmaxf(mx, __shfl_xor(mx, 2));
      mx = fmaxf(mx, __shfl_xor(mx, 4));
      mx = fmaxf(mx, __shfl_xor(mx, 8));
      float mnew = fmaxf(m_r[j], mx);
      scale[j] = __expf(m_r[j] - mnew);
      m_r[j] = mnew;
      float psum = 0.f;
      for (int nt = 0; nt < 4; ++nt) {
        float p = __expf(s[nt][j] - mnew);
        s[nt][j] = p;
        psum += p;
      }
      psum += __shfl_xor(psum, 1);
      psum += __shfl_xor(psum, 2);
      psum += __shfl_xor(psum, 4);
      psum += __shfl_xor(psum, 8);
      l_r[j] = l_r[j] * scale[j] + psum;
    }

    // rescale O
    for (int dt = 0; dt < 8; ++dt)
      for (int j = 0; j < 4; ++j) acc[dt][j] *= scale[j];

    // P: C-layout -> LDS row-major [q_local][kv]  (per-wave buffer, no barrier)
    for (int nt = 0; nt < 4; ++nt)
      for (int j = 0; j < 4; ++j)
        Pl[wave][g * 4 + j][nt * 16 + lr] = (__bf16)s[nt][j];

    // PV: O[q][d] += P[q][kv] * V[kv][d];  kv = 64 -> 2 chunks of 32
    for (int c = 0; c < 2; ++c) {
      bf16x8 pf = *reinterpret_cast<const bf16x8*>(&Pl[wave][lr][c * 32 + g * 8]);
      for (int dt = 0; dt < 8; ++dt) {
        bf16x8 vf = *reinterpret_cast<const bf16x8*>(&Vt[dt * 16 + lr][c * 32 + g * 8]);
        acc[dt] = __builtin_amdgcn_mfma_f32_16x16x32_bf16(pf, vf, acc[dt], 0, 0, 0);
      }
    }
  }

  // epilogue: O / l, write bf16
  float inv_l[4];
  for (int j = 0; j < 4; ++j) inv_l[j] = 1.0f / l_r[j];
  for (int dt = 0; dt < 8; ++dt)
    for (int j = 0; j < 4; ++j) {
      int row = qbase + wave * 16 + g * 4 + j;
      o[((size_t)bh * S_LEN + row) * D_DIM + dt * 16 + lr] =
          (__bf16)(acc[dt][j] * inv_l[j]);
    }
}

// ---------------------------------------------------------------------------
extern "C" void kernel_launch(void* const* d_in, const int* in_sizes, int n_in,
                              void* d_out, int out_size, void* d_ws, size_t ws_size,
                              hipStream_t stream) {
  const float* query = (const float*)d_in[0];
  const float* key_  = (const float*)d_in[1];
  const float* value = (const float*)d_in[2];
  const float* Wq = (const float*)d_in[3];
  const float* bq = (const float*)d_in[4];
  const float* Wk = (const float*)d_in[5];
  const float* bk = (const float*)d_in[6];
  const float* Wv = (const float*)d_in[7];
  const float* bv = (const float*)d_in[8];
  const float* Wo = (const float*)d_in[9];
  const float* bo = (const float*)d_in[10];

  // scratch layout: v + attn-out in d_ws (33.5 MB); q + k scratch inside d_out
  // (bf16, 2 x 16.8 MB = exactly d_out's 33.5 MB; fully overwritten at the end)
  __bf16* vws = (__bf16*)d_ws;
  __bf16* aws = vws + (size_t)NTOK * D_DIM;
  __bf16* qws = (__bf16*)d_out;
  __bf16* kws = qws + (size_t)NTOK * D_DIM;

  const float qscale = 0.08838834764831845f;  // 1/sqrt(128)

  dim3 blk(256);
  proj_kernel<float, __bf16><<<NTOK / 64, blk, 0, stream>>>(query, Wq, bq, qws, qscale);
  proj_kernel<float, __bf16><<<NTOK / 64, blk, 0, stream>>>(key_, Wk, bk, kws, 1.0f);
  proj_kernel<float, __bf16><<<NTOK / 64, blk, 0, stream>>>(value, Wv, bv, vws, 1.0f);

  attn_kernel<<<dim3(S_LEN / 64, 32), blk, 0, stream>>>(qws, kws, vws, aws);

  proj_kernel<__bf16, float><<<NTOK / 64, blk, 0, stream>>>(aws, Wo, bo, (float*)d_out, 1.0f);
}

// Round 2
// 257.994 us; speedup vs baseline: 2.0624x; 2.0624x over previous
//
#include <hip/hip_runtime.h>
#include <hip/hip_bf16.h>
#include <type_traits>

typedef __bf16 bf16x8 __attribute__((ext_vector_type(8)));
typedef float floatx4 __attribute__((ext_vector_type(4)));

#define S_LEN 2048
#define D_DIM 128
#define NTOK (2 * 16 * 2048)  // B*H*S = 65536 rows

// ---------------------------------------------------------------------------
// proj_kernel: y[r,e] = (sum_d x[r,d] * W[e,d] + b[e]) * out_scale
// MFMA 16x16x32 bf16, W staged in LDS as bf16. 256 thr = 4 waves, 64 rows/blk.
// ---------------------------------------------------------------------------
template <typename TIN, typename TOUT>
__global__ __launch_bounds__(256) void proj_kernel(
    const TIN* __restrict__ x, const float* __restrict__ W,
    const float* __restrict__ b, TOUT* __restrict__ y, float out_scale) {
  __shared__ alignas(16) __bf16 Wl[128][128];  // 32 KB

  const int tid = threadIdx.x;
  const int wave = tid >> 6, lane = tid & 63;
  const int g = lane >> 4, lr = lane & 15;

  // stage W fp32 -> bf16 (16384 elems; 256 thr x 4 x 16 iters, coalesced)
  for (int it = 0; it < 16; ++it) {
    int lin = it * 1024 + tid * 4;
    float4 w4 = *reinterpret_cast<const float4*>(W + lin);
    int r = lin >> 7, c = lin & 127;
    Wl[r][c]     = (__bf16)w4.x;
    Wl[r][c + 1] = (__bf16)w4.y;
    Wl[r][c + 2] = (__bf16)w4.z;
    Wl[r][c + 3] = (__bf16)w4.w;
  }
  __syncthreads();

  const int rbase = blockIdx.x * 64;
  const int arow = rbase + wave * 16 + lr;  // A-fragment row (lane&15 = M row)

  floatx4 acc[8];
  for (int i = 0; i < 8; ++i) acc[i] = floatx4{0.f, 0.f, 0.f, 0.f};

  for (int kc = 0; kc < 4; ++kc) {  // K = 128 in 4 chunks of 32
    bf16x8 af;
    const TIN* xp = x + (size_t)arow * D_DIM + kc * 32 + g * 8;
    if constexpr (std::is_same<TIN, float>::value) {
      float4 f0 = *reinterpret_cast<const float4*>(xp);
      float4 f1 = *reinterpret_cast<const float4*>(xp + 4);
      af[0] = (__bf16)f0.x; af[1] = (__bf16)f0.y;
      af[2] = (__bf16)f0.z; af[3] = (__bf16)f0.w;
      af[4] = (__bf16)f1.x; af[5] = (__bf16)f1.y;
      af[6] = (__bf16)f1.z; af[7] = (__bf16)f1.w;
    } else {
      af = *reinterpret_cast<const bf16x8*>(xp);
    }
    for (int nt = 0; nt < 8; ++nt) {  // 8 N-tiles of 16 cols
      bf16x8 wf = *reinterpret_cast<const bf16x8*>(&Wl[nt * 16 + lr][kc * 32 + g * 8]);
      acc[nt] = __builtin_amdgcn_mfma_f32_16x16x32_bf16(af, wf, acc[nt], 0, 0, 0);
    }
  }

  // C/D layout: col = lane&15, row = (lane>>4)*4 + j   [m89-verified]
  for (int nt = 0; nt < 8; ++nt) {
    int e = nt * 16 + lr;
    float be = b[e];
    for (int j = 0; j < 4; ++j) {
      int row = rbase + wave * 16 + g * 4 + j;
      float val = (acc[nt][j] + be) * out_scale;
      y[(size_t)row * D_DIM + e] = (TOUT)val;
    }
  }
}

// ---------------------------------------------------------------------------
// LDS XOR swizzle: flips byte-offset bits 4..6 by (row ^ row>>3).
// Bijective within any 128B-aligned region; preserves 16B alignment.
// Chosen so BOTH strided-row reads (row = f(lane&15)) and the V-transpose
// writes (row = 8*(lane&15)+e, where row&7 is lane-invariant) get spread.
// ---------------------------------------------------------------------------
__device__ __forceinline__ unsigned swz(int row, unsigned byteoff) {
  return byteoff ^ (((unsigned)(row ^ (row >> 3)) & 7u) << 4);
}

// ---------------------------------------------------------------------------
// attn_kernel: flash attention, online softmax. Grid (S/64, B*H), 256 thr.
// Each wave owns 16 Q-rows; block owns 64 Q-rows of one (b,h). KVBLK = 64.
// q is pre-scaled by 1/sqrt(D). All LDS tiles XOR-swizzled (see swz()).
// LDS = 16 + 16 + 8 = 40 KB -> 4 blocks/CU.
// ---------------------------------------------------------------------------
__global__ __launch_bounds__(256) void attn_kernel(
    const __bf16* __restrict__ q, const __bf16* __restrict__ k,
    const __bf16* __restrict__ v, __bf16* __restrict__ o) {
  __shared__ alignas(16) unsigned char Klb[64 * 256];    // 16 KB: K row-major
  __shared__ alignas(16) unsigned char Vtb[128 * 128];   // 16 KB: V transposed
  __shared__ alignas(16) unsigned char Plb[4][16 * 128]; //  8 KB: per-wave P

  const int tid = threadIdx.x;
  const int wave = tid >> 6, lane = tid & 63;
  const int g = lane >> 4, lr = lane & 15;

  const int bh = blockIdx.y;
  const int qbase = blockIdx.x * 64;
  const __bf16* qp = q + (size_t)bh * S_LEN * D_DIM;
  const __bf16* kp = k + (size_t)bh * S_LEN * D_DIM;
  const __bf16* vp = v + (size_t)bh * S_LEN * D_DIM;

  // Q fragments for this wave's 16 rows (A layout: row=lane&15, k=(lane>>4)*8+i)
  const int qrow = qbase + wave * 16 + lr;
  bf16x8 qf[4];
  for (int kc = 0; kc < 4; ++kc)
    qf[kc] = *reinterpret_cast<const bf16x8*>(qp + (size_t)qrow * D_DIM + kc * 32 + g * 8);

  floatx4 acc[8];  // O accumulator: 8 d-tiles x (4 rows/lane)
  for (int i = 0; i < 8; ++i) acc[i] = floatx4{0.f, 0.f, 0.f, 0.f};
  float m_r[4], l_r[4];
  for (int j = 0; j < 4; ++j) { m_r[j] = -1e30f; l_r[j] = 0.f; }

  for (int kv0 = 0; kv0 < S_LEN; kv0 += 64) {
    __syncthreads();  // previous iteration done reading Kl/Vt
    // cooperative load: K row-major (swizzled b128 writes, conflict-free),
    // V transposed (scalar writes, ~4-way after swizzle).
    for (int it = 0; it < 4; ++it) {
      int idx = it * 256 + tid;         // 0..1023
      int r = idx >> 4;                 // kv row 0..63
      int c = (idx & 15) * 8;           // col 0..120
      *reinterpret_cast<bf16x8*>(Klb + swz(r, r * 256u + c * 2u)) =
          *reinterpret_cast<const bf16x8*>(kp + (size_t)(kv0 + r) * D_DIM + c);
      bf16x8 vv = *reinterpret_cast<const bf16x8*>(vp + (size_t)(kv0 + r) * D_DIM + c);
      for (int e = 0; e < 8; ++e) {
        int vrow = c + e;  // d index
        *reinterpret_cast<__bf16*>(Vtb + swz(vrow, vrow * 128u + r * 2u)) = vv[e];
      }
    }
    __syncthreads();

    // QK^T: S-tile 16 rows x 64 cols -> 4 n-tiles, K-dim 128 -> 4 chunks
    floatx4 s[4];
    for (int nt = 0; nt < 4; ++nt) {
      floatx4 sa = floatx4{0.f, 0.f, 0.f, 0.f};
      for (int kc = 0; kc < 4; ++kc) {
        int row = nt * 16 + lr;
        bf16x8 kf = *reinterpret_cast<const bf16x8*>(
            Klb + swz(row, row * 256u + (kc * 32u + g * 8u) * 2u));
        sa = __builtin_amdgcn_mfma_f32_16x16x32_bf16(qf[kc], kf, sa, 0, 0, 0);
      }
      s[nt] = sa;
    }

    // online softmax: row (q-local) = g*4 + j, cols = nt*16 + lr
    float scale[4];
    for (int j = 0; j < 4; ++j) {
      float mx = fmaxf(fmaxf(s[0][j], s[1][j]), fmaxf(s[2][j], s[3][j]));
      mx = fmaxf(mx, __shfl_xor(mx, 1));
      mx = fmaxf(mx, __shfl_xor(mx, 2));
      mx = fmaxf(mx, __shfl_xor(mx, 4));
      mx = fmaxf(mx, __shfl_xor(mx, 8));
      float mnew = fmaxf(m_r[j], mx);
      scale[j] = __expf(m_r[j] - mnew);
      m_r[j] = mnew;
      float psum = 0.f;
      for (int nt = 0; nt < 4; ++nt) {
        float p = __expf(s[nt][j] - mnew);
        s[nt][j] = p;
        psum += p;
      }
      psum += __shfl_xor(psum, 1);
      psum += __shfl_xor(psum, 2);
      psum += __shfl_xor(psum, 4);
      psum += __shfl_xor(psum, 8);
      l_r[j] = l_r[j] * scale[j] + psum;
    }

    // rescale O
    for (int dt = 0; dt < 8; ++dt)
      for (int j = 0; j < 4; ++j) acc[dt][j] *= scale[j];

    // P: C-layout -> LDS row-major [q_local][kv] (per-wave buffer, no barrier)
    for (int nt = 0; nt < 4; ++nt)
      for (int j = 0; j < 4; ++j) {
        int row = g * 4 + j;
        *reinterpret_cast<__bf16*>(
            Plb[wave] + swz(row, row * 128u + (nt * 16u + lr) * 2u)) = (__bf16)s[nt][j];
      }

    // PV: O[q][d] += P[q][kv] * V[kv][d];  kv = 64 -> 2 chunks of 32
    for (int cc = 0; cc < 2; ++cc) {
      bf16x8 pf = *reinterpret_cast<const bf16x8*>(
          Plb[wave] + swz(lr, lr * 128u + (cc * 32u + g * 8u) * 2u));
      for (int dt = 0; dt < 8; ++dt) {
        int row = dt * 16 + lr;
        bf16x8 vf = *reinterpret_cast<const bf16x8*>(
            Vtb + swz(row, row * 128u + (cc * 32u + g * 8u) * 2u));
        acc[dt] = __builtin_amdgcn_mfma_f32_16x16x32_bf16(pf, vf, acc[dt], 0, 0, 0);
      }
    }
  }

  // epilogue: O / l, write bf16
  float inv_l[4];
  for (int j = 0; j < 4; ++j) inv_l[j] = 1.0f / l_r[j];
  for (int dt = 0; dt < 8; ++dt)
    for (int j = 0; j < 4; ++j) {
      int row = qbase + wave * 16 + g * 4 + j;
      o[((size_t)bh * S_LEN + row) * D_DIM + dt * 16 + lr] =
          (__bf16)(acc[dt][j] * inv_l[j]);
    }
}

// ---------------------------------------------------------------------------
extern "C" void kernel_launch(void* const* d_in, const int* in_sizes, int n_in,
                              void* d_out, int out_size, void* d_ws, size_t ws_size,
                              hipStream_t stream) {
  const float* query = (const float*)d_in[0];
  const float* key_  = (const float*)d_in[1];
  const float* value = (const float*)d_in[2];
  const float* Wq = (const float*)d_in[3];
  const float* bq = (const float*)d_in[4];
  const float* Wk = (const float*)d_in[5];
  const float* bk = (const float*)d_in[6];
  const float* Wv = (const float*)d_in[7];
  const float* bv = (const float*)d_in[8];
  const float* Wo = (const float*)d_in[9];
  const float* bo = (const float*)d_in[10];

  // scratch layout: v + attn-out in d_ws (33.5 MB); q + k scratch inside d_out
  // (bf16, 2 x 16.8 MB = exactly d_out's 33.5 MB; fully overwritten at the end)
  __bf16* vws = (__bf16*)d_ws;
  __bf16* aws = vws + (size_t)NTOK * D_DIM;
  __bf16* qws = (__bf16*)d_out;
  __bf16* kws = qws + (size_t)NTOK * D_DIM;

  const float qscale = 0.08838834764831845f;  // 1/sqrt(128)

  dim3 blk(256);
  proj_kernel<float, __bf16><<<NTOK / 64, blk, 0, stream>>>(query, Wq, bq, qws, qscale);
  proj_kernel<float, __bf16><<<NTOK / 64, blk, 0, stream>>>(key_, Wk, bk, kws, 1.0f);
  proj_kernel<float, __bf16><<<NTOK / 64, blk, 0, stream>>>(value, Wv, bv, vws, 1.0f);

  attn_kernel<<<dim3(S_LEN / 64, 32), blk, 0, stream>>>(qws, kws, vws, aws);

  proj_kernel<__bf16, float><<<NTOK / 64, blk, 0, stream>>>(aws, Wo, bo, (float*)d_out, 1.0f);
}